// Round 3
// baseline (116.980 us; speedup 1.0000x reference)
//
#include <hip/hip_runtime.h>

// Problem constants
#define BB 1024      // batch
#define CC 1000      // classes
#define DD 1024      // feature dim
#define MC 4000      // C*K
#define MCP 4096     // padded MC
#define SIGMA_INV (1.0f/10.0f)
#define NT 16        // K-tiles of 64
#define NIT 8        // main-loop iterations (2 K-tiles each)

typedef __attribute__((ext_vector_type(8))) short bf16x8;
typedef __attribute__((ext_vector_type(4))) float f32x4;

#define GLDS16(g, l) __builtin_amdgcn_global_load_lds( \
    (const __attribute__((address_space(1))) void*)(g), \
    (__attribute__((address_space(3))) void*)(l), 16, 0, 0)

#define SBAR()   __builtin_amdgcn_s_barrier()
#define SCHED()  __builtin_amdgcn_sched_barrier(0)
#define PRIO(x)  __builtin_amdgcn_s_setprio(x)

__device__ __forceinline__ unsigned short f2bf(float x) {
  unsigned u = __float_as_uint(x);
  unsigned r = (u + 0x7fffu + ((u >> 16) & 1u)) >> 16;
  return (unsigned short)r;
}

// ---------------- prep: fp32 -> bf16, row sums of squares, zero accumulators ---
__global__ __launch_bounds__(256) void prep_kernel(
    const float* __restrict__ f, const float* __restrict__ centers,
    unsigned short* __restrict__ fbf, unsigned short* __restrict__ wbf,
    float* __restrict__ f_sq, float* __restrict__ w_sq,
    double* __restrict__ acc2)
{
  if (blockIdx.x == 0 && threadIdx.x == 0) { acc2[0] = 0.0; acc2[1] = 0.0; }
  const int wv = threadIdx.x >> 6, lane = threadIdx.x & 63;
  const int row = blockIdx.x * 4 + wv;            // 0..5119
  const float* src = nullptr;
  unsigned short* dst;
  float* sqp;
  if (row < BB) {
    src = f + (size_t)row * DD; dst = fbf + (size_t)row * DD; sqp = f_sq + row;
  } else {
    int wr = row - BB;                             // 0..4095
    dst = wbf + (size_t)wr * DD; sqp = w_sq + wr;
    if (wr < MC) src = centers + (size_t)wr * DD;
  }
  float ssum = 0.f;
#pragma unroll
  for (int p = 0; p < 4; ++p) {
    int idx = p * 256 + lane * 4;
    float4 v = make_float4(0.f, 0.f, 0.f, 0.f);
    if (src) v = *(const float4*)(src + idx);
    ssum += v.x * v.x + v.y * v.y + v.z * v.z + v.w * v.w;
    ushort4 o;
    o.x = f2bf(v.x); o.y = f2bf(v.y); o.z = f2bf(v.z); o.w = f2bf(v.w);
    *(ushort4*)(dst + idx) = o;
  }
#pragma unroll
  for (int s = 32; s; s >>= 1) ssum += __shfl_xor(ssum, s);
  if (lane == 0) *sqp = ssum;
}

// ---------------- unified 256x256 8-phase GEMM --------------------------------
// 8 waves (2M x 4N), per-wave 128x64 output. LDS [set][A/B] 256x64 bf16 tiles,
// XOR-swizzled: [row][slot], slot = chunk ^ (row&7) in 16B units; staging writes
// linear dest with inverse-swizzled global source (both-sides rule).

#define STAGE(SET, AB, SRC, K0, H) do { \
  GLDS16((SRC) + (K0) + soff[(H)*2+0], &lds[SET][AB][doff[(H)*2+0]]); \
  GLDS16((SRC) + (K0) + soff[(H)*2+1], &lds[SET][AB][doff[(H)*2+1]]); \
} while(0)

#define READ_A(SET, MH) do { \
  _Pragma("unroll") for (int ks = 0; ks < 2; ++ks) \
  _Pragma("unroll") for (int m = 0; m < 4; ++m) { \
    int row = wr*128 + ((MH)*4 + m)*16 + rlo; \
    int slot = (ks*4 + rhi) ^ rx; \
    af[ks][m] = *(const bf16x8*)&lds[SET][0][row*64 + slot*8]; \
  } } while(0)

#define READ_B(SET, NH, BW) do { \
  _Pragma("unroll") for (int ks = 0; ks < 2; ++ks) \
  _Pragma("unroll") for (int n = 0; n < 2; ++n) { \
    int row = wc*64 + ((NH)*2 + n)*16 + rlo; \
    int slot = (ks*4 + rhi) ^ rx; \
    BW[ks][n] = *(const bf16x8*)&lds[SET][1][row*64 + slot*8]; \
  } } while(0)

#define MFMA_Q(MH, NH, BW) do { \
  _Pragma("unroll") for (int ks = 0; ks < 2; ++ks) \
  _Pragma("unroll") for (int m = 0; m < 4; ++m) \
  _Pragma("unroll") for (int n = 0; n < 2; ++n) \
    acc[(MH)*4+m][(NH)*2+n] = __builtin_amdgcn_mfma_f32_16x16x32_bf16( \
        af[ks][m], BW[ks][n], acc[(MH)*4+m][(NH)*2+n], 0, 0, 0); \
} while(0)

#define PHASE_MID() do { SCHED(); SBAR(); SCHED(); PRIO(1); } while(0)
#define PHASE_END() do { PRIO(0); SCHED(); SBAR(); SCHED(); } while(0)

__global__ __launch_bounds__(512, 2) void gemm_kernel(
    const unsigned short* __restrict__ fbf, const unsigned short* __restrict__ wbf,
    const float* __restrict__ f_sq, const float* __restrict__ w_sq,
    float* __restrict__ out, double* __restrict__ acc2)
{
  __shared__ __align__(16) unsigned short lds[2][2][256 * 64];  // 128 KiB

  const int tid = threadIdx.x;
  const int lane = tid & 63, wv = tid >> 6;
  const int wr = wv >> 2, wc = wv & 3;
  const int rlo = lane & 15, rhi = lane >> 4, rx = lane & 7;

  const int orig = blockIdx.x;
  const int bid = (orig & 7) * 25 + (orig >> 3);   // 200 = 8*25, bijective XCD swizzle
  const bool is_fw = bid < 64;
  int tr, tc;
  const unsigned short* Abase;
  if (is_fw) {
    tr = bid >> 4; tc = bid & 15;                  // 4 x 16
    Abase = fbf;
  } else {
    int t = bid - 64;                              // 0..135 upper triangle of 16x16
    tr = 0;
    while (t >= 16 - tr) { t -= 16 - tr; ++tr; }
    tc = tr + t;                                   // tc >= tr
    Abase = wbf;
  }
  const unsigned short* Arow = Abase + (size_t)tr * 256 * DD;
  const unsigned short* Brow = wbf  + (size_t)tc * 256 * DD;

  // per-thread staging offsets for (half, i) combos
  int soff[4], doff[4];
#pragma unroll
  for (int h = 0; h < 2; ++h)
#pragma unroll
    for (int i = 0; i < 2; ++i) {
      int idx = h * 1024 + i * 512 + tid;
      int drow = idx >> 3, dslot = idx & 7;
      int schunk = dslot ^ (drow & 7);
      soff[h * 2 + i] = drow * DD + schunk * 8;
      doff[h * 2 + i] = idx * 8;
    }

  f32x4 acc[8][4] = {};
  bf16x8 af[2][4], bw0[2][2], bw1[2][2];

  // prologue: tile0 (A0,B0 all halves) + tile1 B halves; A1 staged in ph1/ph2
  STAGE(0, 0, Arow, 0, 0);
  STAGE(0, 0, Arow, 0, 1);
  STAGE(0, 1, Brow, 0, 0);
  STAGE(0, 1, Brow, 0, 1);
  STAGE(1, 1, Brow, 64, 0);
  STAGE(1, 1, Brow, 64, 1);
  SCHED();
  asm volatile("s_waitcnt vmcnt(4)" ::: "memory");  // tile0 landed; B1 in flight
  SCHED();
  SBAR();
  SCHED();

#pragma unroll 1
  for (int it = 0; it < NIT; ++it) {
    const int ka  = (2 * it + 1) * 64;   // A for set1 tile (this iteration)
    const int kb0 = (2 * it + 2) * 64;   // next set0 tile
    const int kb1 = (2 * it + 3) * 64;   // next set1 tile
    const bool st = (it < NIT - 1);

    // ph1: set0 quad (mh0,nh0); stage A1h0
    READ_A(0, 0); READ_B(0, 0, bw0);
    STAGE(1, 0, Arow, ka, 0);
    PHASE_MID(); MFMA_Q(0, 0, bw0); PHASE_END();

    // ph2: quad (mh0,nh1); stage A1h1
    READ_B(0, 1, bw1);
    STAGE(1, 0, Arow, ka, 1);
    PHASE_MID(); MFMA_Q(0, 1, bw1); PHASE_END();

    // ph3: quad (mh1,nh1); stage next B0h0 (B0 old fully read after ph2)
    READ_A(0, 1);
    if (st) STAGE(0, 1, Brow, kb0, 0);
    PHASE_MID(); MFMA_Q(1, 1, bw1); PHASE_END();

    // ph4: quad (mh1,nh0); stage next B0h1; counted vmcnt before barrier
    if (st) STAGE(0, 1, Brow, kb0, 1);
    PHASE_MID(); MFMA_Q(1, 0, bw0);
    PRIO(0); SCHED();
    if (st) asm volatile("s_waitcnt vmcnt(4)" ::: "memory");
    else    asm volatile("s_waitcnt vmcnt(0)" ::: "memory");
    SCHED(); SBAR(); SCHED();

    // ph5: set1 quad (mh0,nh0); stage next A0h0 (A0 old fully read after ph3)
    READ_A(1, 0); READ_B(1, 0, bw0);
    if (st) STAGE(0, 0, Arow, kb0, 0);
    PHASE_MID(); MFMA_Q(0, 0, bw0); PHASE_END();

    // ph6: quad (mh0,nh1); stage next A0h1
    READ_B(1, 1, bw1);
    if (st) STAGE(0, 0, Arow, kb0, 1);
    PHASE_MID(); MFMA_Q(0, 1, bw1); PHASE_END();

    // ph7: quad (mh1,nh1); stage next B1h0 (B1 old fully read after ph6)
    READ_A(1, 1);
    if (st) STAGE(1, 1, Brow, kb1, 0);
    PHASE_MID(); MFMA_Q(1, 1, bw1); PHASE_END();

    // ph8: quad (mh1,nh0); stage next B1h1; counted vmcnt before barrier
    if (st) STAGE(1, 1, Brow, kb1, 1);
    PHASE_MID(); MFMA_Q(1, 0, bw0);
    PRIO(0); SCHED();
    asm volatile("s_waitcnt vmcnt(4)" ::: "memory");
    SCHED(); SBAR(); SCHED();
  }

  if (is_fw) {
    // dist = exp(-max(f_sq + w_sq - 2fw, 0)/sigma), max over quads of 4 cols
#pragma unroll
    for (int mf = 0; mf < 8; ++mf) {
      int row = tr * 256 + wr * 128 + mf * 16 + rhi * 4;
#pragma unroll
      for (int nf = 0; nf < 4; ++nf) {
        int col = tc * 256 + wc * 64 + nf * 16 + rlo;
        float wsq = w_sq[col];
#pragma unroll
        for (int r = 0; r < 4; ++r) {
          float fn = f_sq[row + r] + wsq - 2.0f * acc[mf][nf][r];
          fn = fmaxf(fn, 0.f);
          float dist = __expf(-fn * SIGMA_INV);
          dist = fmaxf(dist, __shfl_xor(dist, 1));
          dist = fmaxf(dist, __shfl_xor(dist, 2));
          if ((lane & 3) == 0 && col < MC)
            out[(size_t)(row + r) * (CC + 1) + (col >> 2)] = dist;
        }
      }
    }
  } else {
    // upper-triangle stats: s1 = sum(s), s2 = sum((s-1)^2), i<=j only
    double s1 = 0.0, s2 = 0.0;
#pragma unroll
    for (int mf = 0; mf < 8; ++mf) {
      int i0 = tr * 256 + wr * 128 + mf * 16 + rhi * 4;
#pragma unroll
      for (int nf = 0; nf < 4; ++nf) {
        int j = tc * 256 + wc * 64 + nf * 16 + rlo;
        float wsqj = (j < MC) ? w_sq[j] : 0.f;
#pragma unroll
        for (int r = 0; r < 4; ++r) {
          int i = i0 + r;
          if (i < MC && j < MC && j >= i) {
            float s = fmaxf(w_sq[i] + wsqj - 2.0f * acc[mf][nf][r], 0.f);
            s1 += (double)s;
            double d = (double)s - 1.0;
            s2 += d * d;
          }
        }
      }
    }
#pragma unroll
    for (int s = 32; s; s >>= 1) { s1 += __shfl_xor(s1, s); s2 += __shfl_xor(s2, s); }
    double* rbuf = (double*)&lds[0][0][0];   // GEMM done with LDS; reuse
    if (lane == 0) { rbuf[wv] = s1; rbuf[8 + wv] = s2; }
    __syncthreads();
    if (tid == 0) {
      double t1 = 0.0, t2 = 0.0;
#pragma unroll
      for (int w = 0; w < 8; ++w) { t1 += rbuf[w]; t2 += rbuf[8 + w]; }
      atomicAdd(&acc2[0], t1);
      atomicAdd(&acc2[1], t2);
    }
  }
}

// ---------------- finalize: rw scalar + broadcast to out[:,C] -----------------
__global__ __launch_bounds__(256) void finalize_kernel(
    const double* __restrict__ acc2, float* __restrict__ out)
{
  __shared__ float rws;
  if (threadIdx.x == 0) {
    double SS1 = acc2[0], SS2 = acc2[1];
    double denom = 2.0 / ((double)MC * (double)MC - (double)MC);
    double mu = denom * SS1;
    double T = (double)MC * (double)(MC + 1) * 0.5;  // count of i<=j pairs
    double sm1 = SS1 - T;                 // sum(s - 1)
    double dm = mu - 1.0;
    double resid = SS2 - 2.0 * dm * sm1 + T * dm * dm;
    rws = (float)(denom * resid);
  }
  __syncthreads();
  float v = rws;
  for (int b = threadIdx.x; b < BB; b += 256)
    out[(size_t)b * (CC + 1) + CC] = v;
}

// ---------------- launch ------------------------------------------------------
extern "C" void kernel_launch(void* const* d_in, const int* in_sizes, int n_in,
                              void* d_out, int out_size, void* d_ws, size_t ws_size,
                              hipStream_t stream) {
  const float* f = (const float*)d_in[0];
  const float* centers = (const float*)d_in[1];
  float* out = (float*)d_out;
  char* ws = (char*)d_ws;

  double* acc2        = (double*)(ws + 0);
  float* f_sq         = (float*)(ws + 4096);
  float* w_sq         = (float*)(ws + 8192);           // MCP floats
  unsigned short* fbf = (unsigned short*)(ws + 24576); // BB*DD bf16 = 2MB
  unsigned short* wbf = (unsigned short*)(ws + 24576 + 2 * 1024 * 1024); // MCP*DD bf16 = 8MB

  prep_kernel<<<(BB + MCP) / 4, 256, 0, stream>>>(f, centers, fbf, wbf, f_sq, w_sq, acc2);
  gemm_kernel<<<200, 512, 0, stream>>>(fbf, wbf, f_sq, w_sq, out, acc2);
  finalize_kernel<<<1, 256, 0, stream>>>(acc2, out);
}